// Round 5
// baseline (2439.209 us; speedup 1.0000x reference)
//
#include <hip/hip_runtime.h>
#include <hip/hip_cooperative_groups.h>

namespace cg = cooperative_groups;

// GAT 4-layer forward on MI355X — round 5.
// vs round 4:
//  * ONE persistent cooperative kernel; grid.sync() between phases. Kills the
//    ~250us of inter-kernel dispatch/drain overhead (15 launches -> 1).
//  * attn is single-pass: leaky_relu is monotone, so mm = leaky(ALS_BOUND+aa)
//    upper-bounds every edge logit; softmax shift cancels exactly in acc/sw.
//    Deletes the per-node max pass + butterfly.
//  * ELL indices stored as ushort (N < 65536): halves scatter write traffic.

#define MAXDEG 96
#define NGRAPH 64
#define NCU 256
#define BUILD_PASSES 8
#define ALS_BOUND 16.0f

struct GP {
  const float* x; const int* ei; const int* batch;
  const float* W1; const float* as1; const float* ad1; const float* b1;
  const float* W2; const float* as2; const float* ad2; const float* b2;
  const float* W3; const float* as3; const float* ad3; const float* b3;
  const float* W4; const float* as4; const float* ad4; const float* b4;
  float* out;
  int* cursor; int* gstart;
  unsigned short* ell; unsigned short* hbuf;
  float* feat; float* als; float* ald;
  int N; int E;
};

__device__ __forceinline__ float bf2f(unsigned short u) {
  return __uint_as_float(((unsigned int)u) << 16);
}
__device__ __forceinline__ unsigned short f2bf(float f) {
  unsigned int u = __float_as_uint(f);
  u += 0x7fffu + ((u >> 16) & 1u);  // RNE
  return (unsigned short)(u >> 16);
}
__device__ __forceinline__ float lrelu2(float v) { return (v > 0.f) ? v : 0.2f * v; }

// ---------------- phase bodies (device, grid-stride) ----------------

__device__ __forceinline__ void d_init(const GP& p, int tid, int nthr) {
  for (int n = tid; n < p.N; n += nthr) {
    p.cursor[n] = 0;
    int b = p.batch[n];
    if (n == 0) {
      for (int g = 0; g <= b; ++g) p.gstart[g] = 0;
    } else {
      int pb = p.batch[n - 1];
      if (b != pb)
        for (int g = pb + 1; g <= b; ++g) p.gstart[g] = n;
    }
    if (n == p.N - 1) {
      for (int g = b + 1; g <= NGRAPH; ++g) p.gstart[g] = p.N;
    }
  }
}

__device__ __forceinline__ void d_build(const GP& p, int tid, int nthr) {
  int range = (p.N + BUILD_PASSES - 1) / BUILD_PASSES;
  for (int pass = 0; pass < BUILD_PASSES; ++pass) {
    int lo = pass * range;
    int hi = lo + range; if (hi > p.N) hi = p.N;
    for (int e = tid; e < p.E; e += nthr) {
      int dst = p.ei[p.E + e];
      if (dst >= lo && dst < hi) {
        int slot = atomicAdd(&p.cursor[dst], 1);
        if (slot < MAXDEG) p.ell[(size_t)dst * MAXDEG + slot] = (unsigned short)p.ei[e];
      }
    }
  }
}

template <int K, int H>
__device__ __forceinline__ void d_transform(
    const float* __restrict__ xin, const float* __restrict__ W,
    const float* __restrict__ avs, const float* __restrict__ avd,
    unsigned short* __restrict__ hbuf, float* __restrict__ als,
    float* __restrict__ ald, int N, int wave0, int nwaves, int lane) {
  constexpr int C = 64 / H;
  float sA = avs[lane], sD = avd[lane];
  for (int wid = wave0; wid < N; wid += nwaves) {
    const float* xr = xin + (size_t)wid * K;
    float r0 = xr[lane];
    float r1 = (K == 128) ? xr[64 + lane] : 0.f;
    float acc = 0.f;
#pragma unroll
    for (int k = 0; k < K; ++k) {
      float xk = __shfl((k < 64) ? r0 : r1, k & 63, 64);
      acc += xk * W[k * 64 + lane];
    }
    hbuf[(size_t)wid * 64 + lane] = f2bf(acc);
    float ps = acc * sA, pd = acc * sD;
#pragma unroll
    for (int off = 1; off < C; off <<= 1) {
      ps += __shfl_xor(ps, off, 64);
      pd += __shfl_xor(pd, off, 64);
    }
    if ((lane & (C - 1)) == 0) {
      als[wid * H + lane / C] = ps;
      ald[wid * H + lane / C] = pd;
    }
  }
}

// Single-pass attention: mm = leaky(ALS_BOUND + aa) >= every edge logit
// (leaky_relu monotone + als globally bounded). Softmax shift cancels in the
// final acc/sw ratio; only requirement is no overflow/denormal, satisfied for
// exp args in [-40, 0].
template <int H>
__device__ __forceinline__ void d_attn(
    const int* __restrict__ deg, const unsigned short* __restrict__ ell,
    const float* __restrict__ als, const float* __restrict__ ald,
    const unsigned short* __restrict__ hbuf, const float* __restrict__ bias,
    float* __restrict__ feat, int N, int wave0, int nwaves, int lane) {
  constexpr int C = 64 / H;
  int j = lane & 15;   // channel group (channels 4j..4j+3)
  int g = lane >> 4;   // edge substream 0..3
  int hf = (4 * j) / C;
  float4 bv = *(const float4*)(bias + j * 4);
  for (int wid = wave0; wid < N; wid += nwaves) {
    int d = deg[wid];
    if (d > MAXDEG) d = MAXDEG;
    const unsigned short* row = ell + (size_t)wid * MAXDEG;
    float aa = ald[wid * H + hf];
    float ash = als[wid * H + hf];
    float mm = lrelu2(ALS_BOUND + aa);
    float acc0 = 0.f, acc1 = 0.f, acc2 = 0.f, acc3 = 0.f, sw = 0.f;
#pragma unroll 2
    for (int i = 0; i < d; i += 4) {
      ushort4 ss = *(const ushort4*)(row + i);
      int s = (g == 0) ? ss.x : (g == 1) ? ss.y : (g == 2) ? ss.z : ss.w;
      bool valid = (i + g) < d;
      s = valid ? s : wid;
      float v = lrelu2(als[s * H + hf] + aa);
      float w = valid ? __expf(v - mm) : 0.f;
      ushort4 hv = *(const ushort4*)(hbuf + (size_t)s * 64 + j * 4);
      sw += w;
      acc0 += w * bf2f(hv.x);
      acc1 += w * bf2f(hv.y);
      acc2 += w * bf2f(hv.z);
      acc3 += w * bf2f(hv.w);
    }
    sw += __shfl_xor(sw, 16, 64);     sw += __shfl_xor(sw, 32, 64);
    acc0 += __shfl_xor(acc0, 16, 64); acc0 += __shfl_xor(acc0, 32, 64);
    acc1 += __shfl_xor(acc1, 16, 64); acc1 += __shfl_xor(acc1, 32, 64);
    acc2 += __shfl_xor(acc2, 16, 64); acc2 += __shfl_xor(acc2, 32, 64);
    acc3 += __shfl_xor(acc3, 16, 64); acc3 += __shfl_xor(acc3, 32, 64);
    {  // self-loop, added once post-combine (consistent on all lanes)
      float v = lrelu2(ash + aa);
      float w = __expf(v - mm);
      ushort4 hv = *(const ushort4*)(hbuf + (size_t)wid * 64 + j * 4);
      sw += w;
      acc0 += w * bf2f(hv.x);
      acc1 += w * bf2f(hv.y);
      acc2 += w * bf2f(hv.z);
      acc3 += w * bf2f(hv.w);
    }
    if (g == 0) {
      float inv = 1.f / (sw + 1e-16f);
      float4 o;
      o.x = acc0 * inv + bv.x; o.x = (o.x > 0.f) ? o.x : 0.01f * o.x;
      o.y = acc1 * inv + bv.y; o.y = (o.y > 0.f) ? o.y : 0.01f * o.y;
      o.z = acc2 * inv + bv.z; o.z = (o.z > 0.f) ? o.z : 0.01f * o.z;
      o.w = acc3 * inv + bv.w; o.w = (o.w > 0.f) ? o.w : 0.01f * o.w;
      *(float4*)(feat + (size_t)wid * 64 + j * 4) = o;
    }
  }
}

// ---------------- persistent cooperative kernel ----------------

__global__ __launch_bounds__(256, 6) void k_persist(GP p) {
  cg::grid_group grid = cg::this_grid();
  const int tid = blockIdx.x * blockDim.x + threadIdx.x;
  const int nthr = gridDim.x * blockDim.x;
  const int lane = threadIdx.x & 63;
  const int wave0 = tid >> 6;
  const int nwaves = nthr >> 6;
  __shared__ float psum[256];

  d_init(p, tid, nthr);
  grid.sync();
  d_build(p, tid, nthr);
  grid.sync();

  d_transform<128, 4>(p.x, p.W1, p.as1, p.ad1, p.hbuf, p.als, p.ald, p.N, wave0, nwaves, lane);
  grid.sync();
  d_attn<4>(p.cursor, p.ell, p.als, p.ald, p.hbuf, p.b1, p.feat, p.N, wave0, nwaves, lane);
  grid.sync();
  d_transform<64, 4>(p.feat, p.W2, p.as2, p.ad2, p.hbuf, p.als, p.ald, p.N, wave0, nwaves, lane);
  grid.sync();
  d_attn<4>(p.cursor, p.ell, p.als, p.ald, p.hbuf, p.b2, p.feat, p.N, wave0, nwaves, lane);
  grid.sync();
  d_transform<64, 4>(p.feat, p.W3, p.as3, p.ad3, p.hbuf, p.als, p.ald, p.N, wave0, nwaves, lane);
  grid.sync();
  d_attn<4>(p.cursor, p.ell, p.als, p.ald, p.hbuf, p.b3, p.feat, p.N, wave0, nwaves, lane);
  grid.sync();
  d_transform<64, 1>(p.feat, p.W4, p.as4, p.ad4, p.hbuf, p.als, p.ald, p.N, wave0, nwaves, lane);
  grid.sync();
  d_attn<1>(p.cursor, p.ell, p.als, p.ald, p.hbuf, p.b4, p.feat, p.N, wave0, nwaves, lane);
  grid.sync();

  if (blockIdx.x < NGRAPH) {
    int g = blockIdx.x, t = threadIdx.x, f = t & 63, r = t >> 6;
    int s = p.gstart[g], e = p.gstart[g + 1];
    float acc = 0.f;
    for (int n = s + r; n < e; n += 4) acc += p.feat[(size_t)n * 64 + f];
    psum[t] = acc;
    __syncthreads();
    if (r == 0) {
      float tot = psum[f] + psum[64 + f] + psum[128 + f] + psum[192 + f];
      p.out[g * 64 + f] = tot / fmaxf((float)(e - s), 1.0f);
    }
  }
}

// ---------------- discrete-kernel fallback (if coop launch fails) ----------------

__global__ __launch_bounds__(256) void k_init_g(GP p) {
  d_init(p, blockIdx.x * blockDim.x + threadIdx.x, gridDim.x * blockDim.x);
}
__global__ __launch_bounds__(256) void k_build_g(GP p) {
  d_build(p, blockIdx.x * blockDim.x + threadIdx.x, gridDim.x * blockDim.x);
}
template <int K, int H>
__global__ __launch_bounds__(256) void k_T_g(const float* xin, const float* W,
                                             const float* avs, const float* avd,
                                             unsigned short* hbuf, float* als,
                                             float* ald, int N) {
  d_transform<K, H>(xin, W, avs, avd, hbuf, als, ald, N,
                    (blockIdx.x * blockDim.x + threadIdx.x) >> 6,
                    (gridDim.x * blockDim.x) >> 6, threadIdx.x & 63);
}
template <int H>
__global__ __launch_bounds__(256) void k_A_g(const int* deg, const unsigned short* ell,
                                             const float* als, const float* ald,
                                             const unsigned short* hbuf, const float* bias,
                                             float* feat, int N) {
  d_attn<H>(deg, ell, als, ald, hbuf, bias, feat, N,
            (blockIdx.x * blockDim.x + threadIdx.x) >> 6,
            (gridDim.x * blockDim.x) >> 6, threadIdx.x & 63);
}
__global__ __launch_bounds__(256) void k_pool_g(const int* gstart, const float* feat,
                                                float* out) {
  __shared__ float psum[256];
  int g = blockIdx.x, t = threadIdx.x, f = t & 63, r = t >> 6;
  int s = gstart[g], e = gstart[g + 1];
  float acc = 0.f;
  for (int n = s + r; n < e; n += 4) acc += feat[(size_t)n * 64 + f];
  psum[t] = acc;
  __syncthreads();
  if (r == 0) {
    float tot = psum[f] + psum[64 + f] + psum[128 + f] + psum[192 + f];
    out[g * 64 + f] = tot / fmaxf((float)(e - s), 1.0f);
  }
}

// ---------------- launch ----------------

extern "C" void kernel_launch(void* const* d_in, const int* in_sizes, int n_in,
                              void* d_out, int out_size, void* d_ws, size_t ws_size,
                              hipStream_t stream) {
  GP p;
  p.x = (const float*)d_in[0];
  p.ei = (const int*)d_in[1];
  p.batch = (const int*)d_in[2];
  p.W1 = (const float*)d_in[3];  p.as1 = (const float*)d_in[4];
  p.ad1 = (const float*)d_in[5]; p.b1 = (const float*)d_in[6];
  p.W2 = (const float*)d_in[7];  p.as2 = (const float*)d_in[8];
  p.ad2 = (const float*)d_in[9]; p.b2 = (const float*)d_in[10];
  p.W3 = (const float*)d_in[11]; p.as3 = (const float*)d_in[12];
  p.ad3 = (const float*)d_in[13]; p.b3 = (const float*)d_in[14];
  p.W4 = (const float*)d_in[15]; p.as4 = (const float*)d_in[16];
  p.ad4 = (const float*)d_in[17]; p.b4 = (const float*)d_in[18];
  p.out = (float*)d_out;
  p.N = in_sizes[2];
  p.E = in_sizes[1] / 2;

  size_t off = 0;
  auto carve = [&](size_t bytes) {
    void* q = (char*)d_ws + off;
    off = (off + bytes + 255) & ~(size_t)255;
    return q;
  };
  p.cursor = (int*)carve((size_t)p.N * 4);
  p.gstart = (int*)carve((size_t)(NGRAPH + 1) * 4);
  p.ell = (unsigned short*)carve((size_t)p.N * MAXDEG * 2);
  p.hbuf = (unsigned short*)carve((size_t)p.N * 64 * 2);
  p.feat = (float*)carve((size_t)p.N * 64 * 4);
  p.als = (float*)carve((size_t)p.N * 4 * 4);
  p.ald = (float*)carve((size_t)p.N * 4 * 4);
  (void)ws_size;

  int maxb = 0;
  (void)hipOccupancyMaxActiveBlocksPerMultiprocessor(
      &maxb, reinterpret_cast<const void*>(k_persist), 256, 0);
  if (maxb < 1) maxb = 1;
  if (maxb > 8) maxb = 8;
  dim3 grid(NCU * maxb), block(256);
  void* args[] = {(void*)&p};
  hipError_t ce = hipLaunchCooperativeKernel(
      reinterpret_cast<const void*>(k_persist), grid, block, args, 0, stream);

  if (ce != hipSuccess) {
    // discrete fallback
    int nb = (p.N + 255) / 256;
    int wb = (p.N + 3) / 4;
    k_init_g<<<nb, 256, 0, stream>>>(p);
    k_build_g<<<2048, 256, 0, stream>>>(p);
    k_T_g<128, 4><<<wb, 256, 0, stream>>>(p.x, p.W1, p.as1, p.ad1, p.hbuf, p.als, p.ald, p.N);
    k_A_g<4><<<wb, 256, 0, stream>>>(p.cursor, p.ell, p.als, p.ald, p.hbuf, p.b1, p.feat, p.N);
    k_T_g<64, 4><<<wb, 256, 0, stream>>>(p.feat, p.W2, p.as2, p.ad2, p.hbuf, p.als, p.ald, p.N);
    k_A_g<4><<<wb, 256, 0, stream>>>(p.cursor, p.ell, p.als, p.ald, p.hbuf, p.b2, p.feat, p.N);
    k_T_g<64, 4><<<wb, 256, 0, stream>>>(p.feat, p.W3, p.as3, p.ad3, p.hbuf, p.als, p.ald, p.N);
    k_A_g<4><<<wb, 256, 0, stream>>>(p.cursor, p.ell, p.als, p.ald, p.hbuf, p.b3, p.feat, p.N);
    k_T_g<64, 1><<<wb, 256, 0, stream>>>(p.feat, p.W4, p.as4, p.ad4, p.hbuf, p.als, p.ald, p.N);
    k_A_g<1><<<wb, 256, 0, stream>>>(p.cursor, p.ell, p.als, p.ald, p.hbuf, p.b4, p.feat, p.N);
    k_pool_g<<<NGRAPH, 256, 0, stream>>>(p.gstart, p.feat, p.out);
  }
}

// Round 11
// 816.498 us; speedup vs baseline: 2.9874x; 2.9874x over previous
//
#include <hip/hip_runtime.h>

// GAT 4-layer forward on MI355X — round 6 kernel (5th resubmit; rounds 6-10
// hit GPU-broker timeouts, never measured).
// vs round 5: cooperative kernel REVERTED (grid.sync flushes all 8 XCD L2s ->
// 1.2GB refetch, 3.2x slower). Back to discrete kernels, plus:
//  * attn_i + transform_{i+1} fused (transform only needs the node's own row,
//    which attn just computed in registers): 15 launches -> 8, and 3x feat
//    write+read round-trips eliminated.
//  * k_build: XCD-owned dst windows (blockIdx&7 == window). Each ELL/cursor
//    line is written by ONE XCD's L2 only -> partial-line cross-XCD evictions
//    gone; dst stream re-read 8x (streaming, cheap).
//  * cursor zeroed via hipMemsetAsync; gstart folded into k_build.

#define MAXDEG 96
#define NGRAPH 64
#define NB 2048          // grid-stride block count for heavy kernels
#define ALS_BOUND 16.0f  // |als| global bound: als ~ N(0,~1), max over 50k ~ 4.4

__device__ __forceinline__ float bf2f(unsigned short u) {
  return __uint_as_float(((unsigned int)u) << 16);
}
__device__ __forceinline__ unsigned short f2bf(float f) {
  unsigned int u = __float_as_uint(f);
  u += 0x7fffu + ((u >> 16) & 1u);  // RNE
  return (unsigned short)(u >> 16);
}
__device__ __forceinline__ float lrelu2(float v) { return (v > 0.f) ? v : 0.2f * v; }

// ---------------- build: gstart + XCD-windowed ELL scatter ----------------

__global__ __launch_bounds__(256) void k_build(const int* __restrict__ ei,
                                               const int* __restrict__ batch,
                                               int* __restrict__ cursor,
                                               int* __restrict__ gstart,
                                               unsigned short* __restrict__ ell,
                                               int E, int N) {
  int tid = blockIdx.x * blockDim.x + threadIdx.x;
  int nthr = gridDim.x * blockDim.x;
  // graph segment boundaries (batch is sorted)
  for (int n = tid; n < N; n += nthr) {
    int b = batch[n];
    if (n == 0) {
      for (int g = 0; g <= b; ++g) gstart[g] = 0;
    } else {
      int pb = batch[n - 1];
      if (b != pb)
        for (int g = pb + 1; g <= b; ++g) gstart[g] = n;
    }
    if (n == N - 1) {
      for (int g = b + 1; g <= NGRAPH; ++g) gstart[g] = N;
    }
  }
  // XCD-owned dst window: blocks with (blockIdx&7)==w handle window w only.
  int w = blockIdx.x & 7;
  int bg = blockIdx.x >> 3;
  int range = (N + 7) / 8;
  int lo = w * range;
  int hi = lo + range; if (hi > N) hi = N;
  int t = bg * blockDim.x + threadIdx.x;
  int stride = (gridDim.x >> 3) * blockDim.x;
  for (int e = t; e < E; e += stride) {
    int dst = ei[E + e];
    if (dst >= lo && dst < hi) {
      int slot = atomicAdd(&cursor[dst], 1);
      if (slot < MAXDEG) ell[(size_t)dst * MAXDEG + slot] = (unsigned short)ei[e];
    }
  }
}

// ---------------- transform (standalone, layer 1) ----------------

template <int K, int H>
__global__ __launch_bounds__(256) void k_T(
    const float* __restrict__ xin, const float* __restrict__ W,
    const float* __restrict__ avs, const float* __restrict__ avd,
    unsigned short* __restrict__ hbuf, float* __restrict__ als,
    float* __restrict__ ald, int N) {
  constexpr int C = 64 / H;
  int lane = threadIdx.x & 63;
  int wave0 = (blockIdx.x * blockDim.x + threadIdx.x) >> 6;
  int nw = (gridDim.x * blockDim.x) >> 6;
  float sA = avs[lane], sD = avd[lane];
  for (int wid = wave0; wid < N; wid += nw) {
    const float* xr = xin + (size_t)wid * K;
    float r0 = xr[lane];
    float r1 = (K == 128) ? xr[64 + lane] : 0.f;
    float acc = 0.f;
#pragma unroll
    for (int k = 0; k < K; ++k) {
      float xk = __shfl((k < 64) ? r0 : r1, k & 63, 64);
      acc += xk * W[k * 64 + lane];
    }
    hbuf[(size_t)wid * 64 + lane] = f2bf(acc);
    float ps = acc * sA, pd = acc * sD;
#pragma unroll
    for (int off = 1; off < C; off <<= 1) {
      ps += __shfl_xor(ps, off, 64);
      pd += __shfl_xor(pd, off, 64);
    }
    if ((lane & (C - 1)) == 0) {
      als[wid * H + lane / C] = ps;
      ald[wid * H + lane / C] = pd;
    }
  }
}

// ---------------- attn core (device) ----------------
// Single-pass: mm = leaky(ALS_BOUND+aa) upper-bounds all edge logits
// (leaky monotone); shift cancels in acc/sw. Returns o (all lanes hold the
// full channel-group-j result; j = lane&15 -> channels 4j..4j+3).

template <int H>
__device__ __forceinline__ float4 attn_node(
    int wid, int d, const unsigned short* __restrict__ row,
    const float* __restrict__ als, const float* __restrict__ ald,
    const unsigned short* __restrict__ hbuf, const float4 bv,
    int lane, int j, int g) {
  constexpr int C = 64 / H;
  int hf = (4 * j) / C;
  float aa = ald[wid * H + hf];
  float ash = als[wid * H + hf];
  float mm = lrelu2(ALS_BOUND + aa);
  float acc0 = 0.f, acc1 = 0.f, acc2 = 0.f, acc3 = 0.f, sw = 0.f;
#pragma unroll 2
  for (int i = 0; i < d; i += 4) {
    ushort4 ss = *(const ushort4*)(row + i);
    int s = (g == 0) ? ss.x : (g == 1) ? ss.y : (g == 2) ? ss.z : ss.w;
    bool valid = (i + g) < d;
    s = valid ? s : wid;
    float v = lrelu2(als[s * H + hf] + aa);
    float w = valid ? __expf(v - mm) : 0.f;
    ushort4 hv = *(const ushort4*)(hbuf + (size_t)s * 64 + j * 4);
    sw += w;
    acc0 += w * bf2f(hv.x);
    acc1 += w * bf2f(hv.y);
    acc2 += w * bf2f(hv.z);
    acc3 += w * bf2f(hv.w);
  }
  sw += __shfl_xor(sw, 16, 64);     sw += __shfl_xor(sw, 32, 64);
  acc0 += __shfl_xor(acc0, 16, 64); acc0 += __shfl_xor(acc0, 32, 64);
  acc1 += __shfl_xor(acc1, 16, 64); acc1 += __shfl_xor(acc1, 32, 64);
  acc2 += __shfl_xor(acc2, 16, 64); acc2 += __shfl_xor(acc2, 32, 64);
  acc3 += __shfl_xor(acc3, 16, 64); acc3 += __shfl_xor(acc3, 32, 64);
  {  // self-loop once, post-combine (identical on all lanes)
    float v = lrelu2(ash + aa);
    float w = __expf(v - mm);
    ushort4 hv = *(const ushort4*)(hbuf + (size_t)wid * 64 + j * 4);
    sw += w;
    acc0 += w * bf2f(hv.x);
    acc1 += w * bf2f(hv.y);
    acc2 += w * bf2f(hv.z);
    acc3 += w * bf2f(hv.w);
  }
  float inv = 1.f / (sw + 1e-16f);
  float4 o;
  o.x = acc0 * inv + bv.x; o.x = (o.x > 0.f) ? o.x : 0.01f * o.x;
  o.y = acc1 * inv + bv.y; o.y = (o.y > 0.f) ? o.y : 0.01f * o.y;
  o.z = acc2 * inv + bv.z; o.z = (o.z > 0.f) ? o.z : 0.01f * o.z;
  o.w = acc3 * inv + bv.w; o.w = (o.w > 0.f) ? o.w : 0.01f * o.w;
  return o;
}

// ---------------- fused attn(layer i) + transform(layer i+1) ----------------

template <int HA, int HT>
__global__ __launch_bounds__(256) void k_AT(
    const int* __restrict__ deg, const unsigned short* __restrict__ ell,
    const float* __restrict__ als_i, const float* __restrict__ ald_i,
    const unsigned short* __restrict__ hb_i, const float* __restrict__ bias,
    const float* __restrict__ W, const float* __restrict__ avs,
    const float* __restrict__ avd, unsigned short* __restrict__ hb_o,
    float* __restrict__ als_o, float* __restrict__ ald_o, int N) {
  constexpr int CT = 64 / HT;
  int lane = threadIdx.x & 63;
  int j = lane & 15, g = lane >> 4;
  int wave0 = (blockIdx.x * blockDim.x + threadIdx.x) >> 6;
  int nw = (gridDim.x * blockDim.x) >> 6;
  float4 bv = *(const float4*)(bias + j * 4);
  float sA = avs[lane], sD = avd[lane];
  for (int wid = wave0; wid < N; wid += nw) {
    int d = deg[wid];
    if (d > MAXDEG) d = MAXDEG;
    float4 o = attn_node<HA>(wid, d, ell + (size_t)wid * MAXDEG,
                             als_i, ald_i, hb_i, bv, lane, j, g);
    // redistribute: channel c=lane lives in component (c&3) of lane (c>>2)
    int src = lane >> 2;
    float v0 = __shfl(o.x, src, 64), v1 = __shfl(o.y, src, 64);
    float v2 = __shfl(o.z, src, 64), v3 = __shfl(o.w, src, 64);
    int tt = lane & 3;
    float r0 = (tt == 0) ? v0 : (tt == 1) ? v1 : (tt == 2) ? v2 : v3;
    // transform (K=64)
    float acc = 0.f;
#pragma unroll
    for (int k = 0; k < 64; ++k) acc += __shfl(r0, k, 64) * W[k * 64 + lane];
    hb_o[(size_t)wid * 64 + lane] = f2bf(acc);
    float ps = acc * sA, pd = acc * sD;
#pragma unroll
    for (int off = 1; off < CT; off <<= 1) {
      ps += __shfl_xor(ps, off, 64);
      pd += __shfl_xor(pd, off, 64);
    }
    if ((lane & (CT - 1)) == 0) {
      als_o[wid * HT + lane / CT] = ps;
      ald_o[wid * HT + lane / CT] = pd;
    }
  }
}

// ---------------- final attn (layer 4, writes feat) ----------------

template <int H>
__global__ __launch_bounds__(256) void k_A(
    const int* __restrict__ deg, const unsigned short* __restrict__ ell,
    const float* __restrict__ als, const float* __restrict__ ald,
    const unsigned short* __restrict__ hbuf, const float* __restrict__ bias,
    float* __restrict__ feat, int N) {
  int lane = threadIdx.x & 63;
  int j = lane & 15, g = lane >> 4;
  int wave0 = (blockIdx.x * blockDim.x + threadIdx.x) >> 6;
  int nw = (gridDim.x * blockDim.x) >> 6;
  float4 bv = *(const float4*)(bias + j * 4);
  for (int wid = wave0; wid < N; wid += nw) {
    int d = deg[wid];
    if (d > MAXDEG) d = MAXDEG;
    float4 o = attn_node<H>(wid, d, ell + (size_t)wid * MAXDEG,
                            als, ald, hbuf, bv, lane, j, g);
    if (g == 0) *(float4*)(feat + (size_t)wid * 64 + j * 4) = o;
  }
}

// ---------------- pooling ----------------

__global__ __launch_bounds__(256) void k_pool(const int* __restrict__ gstart,
                                              const float* __restrict__ feat,
                                              float* __restrict__ out) {
  __shared__ float psum[256];
  int g = blockIdx.x, t = threadIdx.x, f = t & 63, r = t >> 6;
  int s = gstart[g], e = gstart[g + 1];
  float acc = 0.f;
  for (int n = s + r; n < e; n += 4) acc += feat[(size_t)n * 64 + f];
  psum[t] = acc;
  __syncthreads();
  if (r == 0) {
    float tot = psum[f] + psum[64 + f] + psum[128 + f] + psum[192 + f];
    out[g * 64 + f] = tot / fmaxf((float)(e - s), 1.0f);
  }
}

// ---------------- launch ----------------

extern "C" void kernel_launch(void* const* d_in, const int* in_sizes, int n_in,
                              void* d_out, int out_size, void* d_ws, size_t ws_size,
                              hipStream_t stream) {
  const float* x = (const float*)d_in[0];
  const int* ei = (const int*)d_in[1];
  const int* batch = (const int*)d_in[2];
  const float* W1 = (const float*)d_in[3];
  const float* as1 = (const float*)d_in[4];
  const float* ad1 = (const float*)d_in[5];
  const float* b1 = (const float*)d_in[6];
  const float* W2 = (const float*)d_in[7];
  const float* as2 = (const float*)d_in[8];
  const float* ad2 = (const float*)d_in[9];
  const float* b2 = (const float*)d_in[10];
  const float* W3 = (const float*)d_in[11];
  const float* as3 = (const float*)d_in[12];
  const float* ad3 = (const float*)d_in[13];
  const float* b3 = (const float*)d_in[14];
  const float* W4 = (const float*)d_in[15];
  const float* as4 = (const float*)d_in[16];
  const float* ad4 = (const float*)d_in[17];
  const float* b4 = (const float*)d_in[18];
  float* out = (float*)d_out;

  const int N = in_sizes[2];
  const int E = in_sizes[1] / 2;

  size_t off = 0;
  auto carve = [&](size_t bytes) {
    void* q = (char*)d_ws + off;
    off = (off + bytes + 255) & ~(size_t)255;
    return q;
  };
  int* cursor = (int*)carve((size_t)N * 4);
  int* gstart = (int*)carve((size_t)(NGRAPH + 1) * 4);
  unsigned short* ell = (unsigned short*)carve((size_t)N * MAXDEG * 2);
  unsigned short* hbufA = (unsigned short*)carve((size_t)N * 64 * 2);
  unsigned short* hbufB = (unsigned short*)carve((size_t)N * 64 * 2);
  float* alsA = (float*)carve((size_t)N * 4 * 4);
  float* aldA = (float*)carve((size_t)N * 4 * 4);
  float* alsB = (float*)carve((size_t)N * 4 * 4);
  float* aldB = (float*)carve((size_t)N * 4 * 4);
  float* feat = (float*)carve((size_t)N * 64 * 4);
  (void)ws_size;

  hipMemsetAsync(cursor, 0, (size_t)N * 4, stream);
  k_build<<<NB, 256, 0, stream>>>(ei, batch, cursor, gstart, ell, E, N);

  // L1 transform
  k_T<128, 4><<<NB, 256, 0, stream>>>(x, W1, as1, ad1, hbufA, alsA, aldA, N);
  // A1 + T2
  k_AT<4, 4><<<NB, 256, 0, stream>>>(cursor, ell, alsA, aldA, hbufA, b1,
                                     W2, as2, ad2, hbufB, alsB, aldB, N);
  // A2 + T3
  k_AT<4, 4><<<NB, 256, 0, stream>>>(cursor, ell, alsB, aldB, hbufB, b2,
                                     W3, as3, ad3, hbufA, alsA, aldA, N);
  // A3 + T4 (layer 4 has H=1)
  k_AT<4, 1><<<NB, 256, 0, stream>>>(cursor, ell, alsA, aldA, hbufA, b3,
                                     W4, as4, ad4, hbufB, alsB, aldB, N);
  // A4 -> feat
  k_A<1><<<NB, 256, 0, stream>>>(cursor, ell, alsB, aldB, hbufB, b4, feat, N);

  k_pool<<<NGRAPH, 256, 0, stream>>>(gstart, feat, out);
}

// Round 14
// 617.373 us; speedup vs baseline: 3.9509x; 1.3225x over previous
//
#include <hip/hip_runtime.h>

// GAT 4-layer forward on MI355X — round 12 kernel (2nd resubmit; broker
// timeouts rounds 12-13).
// vs round 11 (measured): A+T register fusion REVERTED — VGPR 84 -> occupancy
// 27.6% -> 157us (slower than unfused parts). Keep: ushort ELL, XCD-windowed
// build, single-pass softmax (all validated).
// NEW: attn uses 8 edge-substreams x 8-channel groups, uint4 (16B) bf16
// gathers: per-edge VMEM lane-ops halved (24 vs 48), 8 gathers in flight.

#define MAXDEG 96
#define NGRAPH 64
#define NB 2048          // k_build grid
#define ALS_BOUND 16.0f  // |als| bound: als ~ N(0,~1), max over 50k ~ 4.4

__device__ __forceinline__ unsigned short f2bf(float f) {
  unsigned int u = __float_as_uint(f);
  u += 0x7fffu + ((u >> 16) & 1u);  // RNE
  return (unsigned short)(u >> 16);
}
__device__ __forceinline__ float lrelu2(float v) { return (v > 0.f) ? v : 0.2f * v; }

// ---------------- build: gstart + XCD-windowed ELL scatter ----------------

__global__ __launch_bounds__(256) void k_build(const int* __restrict__ ei,
                                               const int* __restrict__ batch,
                                               int* __restrict__ cursor,
                                               int* __restrict__ gstart,
                                               unsigned short* __restrict__ ell,
                                               int E, int N) {
  int tid = blockIdx.x * blockDim.x + threadIdx.x;
  int nthr = gridDim.x * blockDim.x;
  for (int n = tid; n < N; n += nthr) {
    int b = batch[n];
    if (n == 0) {
      for (int g = 0; g <= b; ++g) gstart[g] = 0;
    } else {
      int pb = batch[n - 1];
      if (b != pb)
        for (int g = pb + 1; g <= b; ++g) gstart[g] = n;
    }
    if (n == N - 1) {
      for (int g = b + 1; g <= NGRAPH; ++g) gstart[g] = N;
    }
  }
  // XCD-owned dst window (blockIdx&7 == window w): each ELL/cursor line is
  // written from one XCD's L2 only -> full-line merging before eviction.
  int w = blockIdx.x & 7;
  int bg = blockIdx.x >> 3;
  int range = (N + 7) / 8;
  int lo = w * range;
  int hi = lo + range; if (hi > N) hi = N;
  int t = bg * blockDim.x + threadIdx.x;
  int stride = (gridDim.x >> 3) * blockDim.x;
  for (int e = t; e < E; e += stride) {
    int dst = ei[E + e];
    if (dst >= lo && dst < hi) {
      int slot = atomicAdd(&cursor[dst], 1);
      if (slot < MAXDEG) ell[(size_t)dst * MAXDEG + slot] = (unsigned short)ei[e];
    }
  }
}

// ---------------- transform ----------------

template <int K, int H>
__global__ __launch_bounds__(256) void k_T(
    const float* __restrict__ xin, const float* __restrict__ W,
    const float* __restrict__ avs, const float* __restrict__ avd,
    unsigned short* __restrict__ hbuf, float* __restrict__ als,
    float* __restrict__ ald, int N) {
  constexpr int C = 64 / H;
  int lane = threadIdx.x & 63;
  int wid = (blockIdx.x * blockDim.x + threadIdx.x) >> 6;
  if (wid >= N) return;
  float sA = avs[lane], sD = avd[lane];
  const float* xr = xin + (size_t)wid * K;
  float r0 = xr[lane];
  float r1 = (K == 128) ? xr[64 + lane] : 0.f;
  float acc = 0.f;
#pragma unroll
  for (int k = 0; k < K; ++k) {
    float xk = __shfl((k < 64) ? r0 : r1, k & 63, 64);
    acc += xk * W[k * 64 + lane];
  }
  hbuf[(size_t)wid * 64 + lane] = f2bf(acc);
  float ps = acc * sA, pd = acc * sD;
#pragma unroll
  for (int off = 1; off < C; off <<= 1) {
    ps += __shfl_xor(ps, off, 64);
    pd += __shfl_xor(pd, off, 64);
  }
  if ((lane & (C - 1)) == 0) {
    als[wid * H + lane / C] = ps;
    ald[wid * H + lane / C] = pd;
  }
}

// ---------------- attention: 8 substreams x 8-channel groups ----------------
// One wave per dst node. lane = [substream g = lane>>3 | channel group
// j = lane&7 -> channels 8j..8j+7]. Per iteration: 8 edges, each lane does
// one uint4 (16B, 8 bf16) gather + one als gather. Single-pass softmax:
// mm = lrelu(ALS_BOUND+aa) upper-bounds all logits (lrelu monotone); the
// shift cancels exactly in acc/sw.

template <int H>
__global__ __launch_bounds__(256) void k_A(
    const int* __restrict__ deg, const unsigned short* __restrict__ ell,
    const float* __restrict__ als, const float* __restrict__ ald,
    const unsigned short* __restrict__ hbuf, const float* __restrict__ bias,
    float* __restrict__ feat, int N) {
  constexpr int C = 64 / H;
  int lane = threadIdx.x & 63;
  int wid = (blockIdx.x * blockDim.x + threadIdx.x) >> 6;
  if (wid >= N) return;
  int j = lane & 7;    // channel group: channels 8j..8j+7 (within one head)
  int g = lane >> 3;   // edge substream 0..7
  int hf = (8 * j) / C;
  int d = deg[wid];
  if (d > MAXDEG) d = MAXDEG;
  const unsigned short* row = ell + (size_t)wid * MAXDEG;
  float aa = ald[wid * H + hf];
  float ash = als[wid * H + hf];
  float mm = lrelu2(ALS_BOUND + aa);
  float a0 = 0.f, a1 = 0.f, a2 = 0.f, a3 = 0.f;
  float a4 = 0.f, a5 = 0.f, a6 = 0.f, a7 = 0.f, sw = 0.f;
  for (int i = 0; i < d; i += 8) {
    uint4 iv = *(const uint4*)(row + i);  // 8 ushort indices (broadcast load)
    unsigned int word = ((g >> 1) == 0) ? iv.x : ((g >> 1) == 1) ? iv.y
                        : ((g >> 1) == 2) ? iv.z : iv.w;
    int s = (g & 1) ? (int)(word >> 16) : (int)(word & 0xffffu);
    bool valid = (i + g) < d;
    s = valid ? s : wid;
    float v = lrelu2(als[s * H + hf] + aa);
    float wgt = valid ? __expf(v - mm) : 0.f;
    uint4 hv = *(const uint4*)(hbuf + (size_t)s * 64 + j * 8);  // 8 bf16
    sw += wgt;
    a0 += wgt * __uint_as_float(hv.x << 16);
    a1 += wgt * __uint_as_float(hv.x & 0xffff0000u);
    a2 += wgt * __uint_as_float(hv.y << 16);
    a3 += wgt * __uint_as_float(hv.y & 0xffff0000u);
    a4 += wgt * __uint_as_float(hv.z << 16);
    a5 += wgt * __uint_as_float(hv.z & 0xffff0000u);
    a6 += wgt * __uint_as_float(hv.w << 16);
    a7 += wgt * __uint_as_float(hv.w & 0xffff0000u);
  }
  // combine 8 substreams: xor over bits 3,4,5
#pragma unroll
  for (int off = 8; off < 64; off <<= 1) {
    sw += __shfl_xor(sw, off, 64);
    a0 += __shfl_xor(a0, off, 64);
    a1 += __shfl_xor(a1, off, 64);
    a2 += __shfl_xor(a2, off, 64);
    a3 += __shfl_xor(a3, off, 64);
    a4 += __shfl_xor(a4, off, 64);
    a5 += __shfl_xor(a5, off, 64);
    a6 += __shfl_xor(a6, off, 64);
    a7 += __shfl_xor(a7, off, 64);
  }
  {  // self-loop once, post-combine (identical on all lanes)
    float v = lrelu2(ash + aa);
    float wgt = __expf(v - mm);
    uint4 hv = *(const uint4*)(hbuf + (size_t)wid * 64 + j * 8);
    sw += wgt;
    a0 += wgt * __uint_as_float(hv.x << 16);
    a1 += wgt * __uint_as_float(hv.x & 0xffff0000u);
    a2 += wgt * __uint_as_float(hv.y << 16);
    a3 += wgt * __uint_as_float(hv.y & 0xffff0000u);
    a4 += wgt * __uint_as_float(hv.z << 16);
    a5 += wgt * __uint_as_float(hv.z & 0xffff0000u);
    a6 += wgt * __uint_as_float(hv.w << 16);
    a7 += wgt * __uint_as_float(hv.w & 0xffff0000u);
  }
  float inv = 1.f / (sw + 1e-16f);
  if (g == 0) {  // lanes 0..7: channels 8j..8j+3
    const float4 bv = *(const float4*)(bias + j * 8);
    float4 o;
    o.x = a0 * inv + bv.x; o.x = (o.x > 0.f) ? o.x : 0.01f * o.x;
    o.y = a1 * inv + bv.y; o.y = (o.y > 0.f) ? o.y : 0.01f * o.y;
    o.z = a2 * inv + bv.z; o.z = (o.z > 0.f) ? o.z : 0.01f * o.z;
    o.w = a3 * inv + bv.w; o.w = (o.w > 0.f) ? o.w : 0.01f * o.w;
    *(float4*)(feat + (size_t)wid * 64 + j * 8) = o;
  } else if (g == 1) {  // lanes 8..15: channels 8j+4..8j+7
    const float4 bv = *(const float4*)(bias + j * 8 + 4);
    float4 o;
    o.x = a4 * inv + bv.x; o.x = (o.x > 0.f) ? o.x : 0.01f * o.x;
    o.y = a5 * inv + bv.y; o.y = (o.y > 0.f) ? o.y : 0.01f * o.y;
    o.z = a6 * inv + bv.z; o.z = (o.z > 0.f) ? o.z : 0.01f * o.z;
    o.w = a7 * inv + bv.w; o.w = (o.w > 0.f) ? o.w : 0.01f * o.w;
    *(float4*)(feat + (size_t)wid * 64 + j * 8 + 4) = o;
  }
}

// ---------------- pooling ----------------

__global__ __launch_bounds__(256) void k_pool(const int* __restrict__ gstart,
                                              const float* __restrict__ feat,
                                              float* __restrict__ out) {
  __shared__ float psum[256];
  int g = blockIdx.x, t = threadIdx.x, f = t & 63, r = t >> 6;
  int s = gstart[g], e = gstart[g + 1];
  float acc = 0.f;
  for (int n = s + r; n < e; n += 4) acc += feat[(size_t)n * 64 + f];
  psum[t] = acc;
  __syncthreads();
  if (r == 0) {
    float tot = psum[f] + psum[64 + f] + psum[128 + f] + psum[192 + f];
    out[g * 64 + f] = tot / fmaxf((float)(e - s), 1.0f);
  }
}

// ---------------- launch ----------------

extern "C" void kernel_launch(void* const* d_in, const int* in_sizes, int n_in,
                              void* d_out, int out_size, void* d_ws, size_t ws_size,
                              hipStream_t stream) {
  const float* x = (const float*)d_in[0];
  const int* ei = (const int*)d_in[1];
  const int* batch = (const int*)d_in[2];
  const float* W1 = (const float*)d_in[3];
  const float* as1 = (const float*)d_in[4];
  const float* ad1 = (const float*)d_in[5];
  const float* b1 = (const float*)d_in[6];
  const float* W2 = (const float*)d_in[7];
  const float* as2 = (const float*)d_in[8];
  const float* ad2 = (const float*)d_in[9];
  const float* b2 = (const float*)d_in[10];
  const float* W3 = (const float*)d_in[11];
  const float* as3 = (const float*)d_in[12];
  const float* ad3 = (const float*)d_in[13];
  const float* b3 = (const float*)d_in[14];
  const float* W4 = (const float*)d_in[15];
  const float* as4 = (const float*)d_in[16];
  const float* ad4 = (const float*)d_in[17];
  const float* b4 = (const float*)d_in[18];
  float* out = (float*)d_out;

  const int N = in_sizes[2];
  const int E = in_sizes[1] / 2;

  size_t off = 0;
  auto carve = [&](size_t bytes) {
    void* q = (char*)d_ws + off;
    off = (off + bytes + 255) & ~(size_t)255;
    return q;
  };
  int* cursor = (int*)carve((size_t)N * 4);
  int* gstart = (int*)carve((size_t)(NGRAPH + 1) * 4);
  unsigned short* ell = (unsigned short*)carve((size_t)N * MAXDEG * 2);
  unsigned short* hbuf = (unsigned short*)carve((size_t)N * 64 * 2);
  float* als = (float*)carve((size_t)N * 4 * 4);
  float* ald = (float*)carve((size_t)N * 4 * 4);
  float* feat = (float*)carve((size_t)N * 64 * 4);
  (void)ws_size;

  int wb = (N + 3) / 4;  // one wave per node, 4 waves/block

  hipMemsetAsync(cursor, 0, (size_t)N * 4, stream);
  k_build<<<NB, 256, 0, stream>>>(ei, batch, cursor, gstart, ell, E, N);

  k_T<128, 4><<<wb, 256, 0, stream>>>(x, W1, as1, ad1, hbuf, als, ald, N);
  k_A<4><<<wb, 256, 0, stream>>>(cursor, ell, als, ald, hbuf, b1, feat, N);
  k_T<64, 4><<<wb, 256, 0, stream>>>(feat, W2, as2, ad2, hbuf, als, ald, N);
  k_A<4><<<wb, 256, 0, stream>>>(cursor, ell, als, ald, hbuf, b2, feat, N);
  k_T<64, 4><<<wb, 256, 0, stream>>>(feat, W3, as3, ad3, hbuf, als, ald, N);
  k_A<4><<<wb, 256, 0, stream>>>(cursor, ell, als, ald, hbuf, b3, feat, N);
  k_T<64, 1><<<wb, 256, 0, stream>>>(feat, W4, as4, ad4, hbuf, als, ald, N);
  k_A<1><<<wb, 256, 0, stream>>>(cursor, ell, als, ald, hbuf, b4, feat, N);

  k_pool<<<NGRAPH, 256, 0, stream>>>(gstart, feat, out);
}

// Round 15
// 529.550 us; speedup vs baseline: 4.6062x; 1.1658x over previous
//
#include <hip/hip_runtime.h>

// GAT 4-layer forward on MI355X — round 15.
// vs round 14 (measured 617us): k_T is now the top dispatch (81us x4,
// VALUBusy 21%) — issue-bound on 64 W-loads + 64 shfl-broadcasts per node.
// NEW k_T: W column held in VGPRs per wave (fp32 for K=64; packed bf16 for
// K=128), x row read via wave-uniform scalar loads (readfirstlane'd offset
// -> s_load), inner loop = pure v_fmac with SGPR operand. Grid-stride
// (1024 blocks) so the one-time W load amortizes over ~12 nodes/wave.
// k_A / k_build / k_pool unchanged from round 14.

#define MAXDEG 96
#define NGRAPH 64
#define NB 2048          // k_build grid
#define TB 1024          // k_T grid (4096 waves, ~12 nodes each)
#define ALS_BOUND 16.0f  // |als| bound: als ~ N(0,~1), max over 50k ~ 4.4

__device__ __forceinline__ unsigned short f2bf(float f) {
  unsigned int u = __float_as_uint(f);
  u += 0x7fffu + ((u >> 16) & 1u);  // RNE
  return (unsigned short)(u >> 16);
}
__device__ __forceinline__ float lrelu2(float v) { return (v > 0.f) ? v : 0.2f * v; }

// ---------------- build: gstart + XCD-windowed ELL scatter ----------------

__global__ __launch_bounds__(256) void k_build(const int* __restrict__ ei,
                                               const int* __restrict__ batch,
                                               int* __restrict__ cursor,
                                               int* __restrict__ gstart,
                                               unsigned short* __restrict__ ell,
                                               int E, int N) {
  int tid = blockIdx.x * blockDim.x + threadIdx.x;
  int nthr = gridDim.x * blockDim.x;
  for (int n = tid; n < N; n += nthr) {
    int b = batch[n];
    if (n == 0) {
      for (int g = 0; g <= b; ++g) gstart[g] = 0;
    } else {
      int pb = batch[n - 1];
      if (b != pb)
        for (int g = pb + 1; g <= b; ++g) gstart[g] = n;
    }
    if (n == N - 1) {
      for (int g = b + 1; g <= NGRAPH; ++g) gstart[g] = N;
    }
  }
  // XCD-owned dst window (blockIdx&7 == window w): each ELL/cursor line is
  // written from one XCD's L2 only -> full-line merging before eviction.
  int w = blockIdx.x & 7;
  int bg = blockIdx.x >> 3;
  int range = (N + 7) / 8;
  int lo = w * range;
  int hi = lo + range; if (hi > N) hi = N;
  int t = bg * blockDim.x + threadIdx.x;
  int stride = (gridDim.x >> 3) * blockDim.x;
  for (int e = t; e < E; e += stride) {
    int dst = ei[E + e];
    if (dst >= lo && dst < hi) {
      int slot = atomicAdd(&cursor[dst], 1);
      if (slot < MAXDEG) ell[(size_t)dst * MAXDEG + slot] = (unsigned short)ei[e];
    }
  }
}

// ---------------- transform: W-in-registers + scalar x loads ----------------
// lane = output channel. W[:,lane] lives in VGPRs across the node loop
// (fp32 for K=64, packed bf16 pairs for K=128 to stay at 64 regs). The x-row
// pointer is wave-uniform (readfirstlane'd byte offset) so x loads go to the
// scalar pipe; the K-loop is v_fmac with an SGPR multiplicand.

template <int K, int H>
__global__ __launch_bounds__(256) void k_T(
    const float* __restrict__ xin, const float* __restrict__ W,
    const float* __restrict__ avs, const float* __restrict__ avd,
    unsigned short* __restrict__ hbuf, float* __restrict__ als,
    float* __restrict__ ald, int N) {
  constexpr int C = 64 / H;
  int lane = threadIdx.x & 63;
  int wave0 = (blockIdx.x * blockDim.x + threadIdx.x) >> 6;
  int nw = (gridDim.x * blockDim.x) >> 6;
  float sA = avs[lane], sD = avd[lane];

  float wf[K == 64 ? 64 : 1];          // fp32 W column (K=64 layers)
  unsigned int wp[K == 128 ? 64 : 1];  // packed-bf16 W column (K=128 layer)
  if constexpr (K == 64) {
#pragma unroll
    for (int k = 0; k < 64; ++k) wf[k] = W[k * 64 + lane];
  } else {
#pragma unroll
    for (int kk = 0; kk < 64; ++kk) {
      float w0 = W[(2 * kk) * 64 + lane];
      float w1 = W[(2 * kk + 1) * 64 + lane];
      wp[kk] = ((unsigned)f2bf(w0)) | (((unsigned)f2bf(w1)) << 16);
    }
  }

  for (int wid = wave0; wid < N; wid += nw) {
    unsigned int boff =
        __builtin_amdgcn_readfirstlane((unsigned int)(wid * (K * 4)));
    const float* xr = (const float*)((const char*)xin + boff);
    float acc = 0.f;
    if constexpr (K == 64) {
#pragma unroll
      for (int k = 0; k < 64; ++k) acc += xr[k] * wf[k];
    } else {
#pragma unroll
      for (int kk = 0; kk < 64; ++kk) {
        unsigned int w = wp[kk];
        acc += xr[2 * kk] * __uint_as_float(w << 16);
        acc += xr[2 * kk + 1] * __uint_as_float(w & 0xffff0000u);
      }
    }
    hbuf[(size_t)wid * 64 + lane] = f2bf(acc);
    float ps = acc * sA, pd = acc * sD;
#pragma unroll
    for (int off = 1; off < C; off <<= 1) {
      ps += __shfl_xor(ps, off, 64);
      pd += __shfl_xor(pd, off, 64);
    }
    if ((lane & (C - 1)) == 0) {
      als[wid * H + lane / C] = ps;
      ald[wid * H + lane / C] = pd;
    }
  }
}

// ---------------- attention: 8 substreams x 8-channel groups ----------------
// One wave per dst node. lane = [substream g = lane>>3 | channel group
// j = lane&7 -> channels 8j..8j+7]. Per iteration: 8 edges, each lane does
// one uint4 (16B, 8 bf16) gather + one als gather. Single-pass softmax:
// mm = lrelu(ALS_BOUND+aa) upper-bounds all logits (lrelu monotone); the
// shift cancels exactly in acc/sw.

template <int H>
__global__ __launch_bounds__(256) void k_A(
    const int* __restrict__ deg, const unsigned short* __restrict__ ell,
    const float* __restrict__ als, const float* __restrict__ ald,
    const unsigned short* __restrict__ hbuf, const float* __restrict__ bias,
    float* __restrict__ feat, int N) {
  constexpr int C = 64 / H;
  int lane = threadIdx.x & 63;
  int wid = (blockIdx.x * blockDim.x + threadIdx.x) >> 6;
  if (wid >= N) return;
  int j = lane & 7;    // channel group: channels 8j..8j+7 (within one head)
  int g = lane >> 3;   // edge substream 0..7
  int hf = (8 * j) / C;
  int d = deg[wid];
  if (d > MAXDEG) d = MAXDEG;
  const unsigned short* row = ell + (size_t)wid * MAXDEG;
  float aa = ald[wid * H + hf];
  float ash = als[wid * H + hf];
  float mm = lrelu2(ALS_BOUND + aa);
  float a0 = 0.f, a1 = 0.f, a2 = 0.f, a3 = 0.f;
  float a4 = 0.f, a5 = 0.f, a6 = 0.f, a7 = 0.f, sw = 0.f;
  for (int i = 0; i < d; i += 8) {
    uint4 iv = *(const uint4*)(row + i);  // 8 ushort indices (broadcast load)
    unsigned int word = ((g >> 1) == 0) ? iv.x : ((g >> 1) == 1) ? iv.y
                        : ((g >> 1) == 2) ? iv.z : iv.w;
    int s = (g & 1) ? (int)(word >> 16) : (int)(word & 0xffffu);
    bool valid = (i + g) < d;
    s = valid ? s : wid;
    float v = lrelu2(als[s * H + hf] + aa);
    float wgt = valid ? __expf(v - mm) : 0.f;
    uint4 hv = *(const uint4*)(hbuf + (size_t)s * 64 + j * 8);  // 8 bf16
    sw += wgt;
    a0 += wgt * __uint_as_float(hv.x << 16);
    a1 += wgt * __uint_as_float(hv.x & 0xffff0000u);
    a2 += wgt * __uint_as_float(hv.y << 16);
    a3 += wgt * __uint_as_float(hv.y & 0xffff0000u);
    a4 += wgt * __uint_as_float(hv.z << 16);
    a5 += wgt * __uint_as_float(hv.z & 0xffff0000u);
    a6 += wgt * __uint_as_float(hv.w << 16);
    a7 += wgt * __uint_as_float(hv.w & 0xffff0000u);
  }
  // combine 8 substreams: xor over bits 3,4,5
#pragma unroll
  for (int off = 8; off < 64; off <<= 1) {
    sw += __shfl_xor(sw, off, 64);
    a0 += __shfl_xor(a0, off, 64);
    a1 += __shfl_xor(a1, off, 64);
    a2 += __shfl_xor(a2, off, 64);
    a3 += __shfl_xor(a3, off, 64);
    a4 += __shfl_xor(a4, off, 64);
    a5 += __shfl_xor(a5, off, 64);
    a6 += __shfl_xor(a6, off, 64);
    a7 += __shfl_xor(a7, off, 64);
  }
  {  // self-loop once, post-combine (identical on all lanes)
    float v = lrelu2(ash + aa);
    float wgt = __expf(v - mm);
    uint4 hv = *(const uint4*)(hbuf + (size_t)wid * 64 + j * 8);
    sw += wgt;
    a0 += wgt * __uint_as_float(hv.x << 16);
    a1 += wgt * __uint_as_float(hv.x & 0xffff0000u);
    a2 += wgt * __uint_as_float(hv.y << 16);
    a3 += wgt * __uint_as_float(hv.y & 0xffff0000u);
    a4 += wgt * __uint_as_float(hv.z << 16);
    a5 += wgt * __uint_as_float(hv.z & 0xffff0000u);
    a6 += wgt * __uint_as_float(hv.w << 16);
    a7 += wgt * __uint_as_float(hv.w & 0xffff0000u);
  }
  float inv = 1.f / (sw + 1e-16f);
  if (g == 0) {  // lanes 0..7: channels 8j..8j+3
    const float4 bv = *(const float4*)(bias + j * 8);
    float4 o;
    o.x = a0 * inv + bv.x; o.x = (o.x > 0.f) ? o.x : 0.01f * o.x;
    o.y = a1 * inv + bv.y; o.y = (o.y > 0.f) ? o.y : 0.01f * o.y;
    o.z = a2 * inv + bv.z; o.z = (o.z > 0.f) ? o.z : 0.01f * o.z;
    o.w = a3 * inv + bv.w; o.w = (o.w > 0.f) ? o.w : 0.01f * o.w;
    *(float4*)(feat + (size_t)wid * 64 + j * 8) = o;
  } else if (g == 1) {  // lanes 8..15: channels 8j+4..8j+7
    const float4 bv = *(const float4*)(bias + j * 8 + 4);
    float4 o;
    o.x = a4 * inv + bv.x; o.x = (o.x > 0.f) ? o.x : 0.01f * o.x;
    o.y = a5 * inv + bv.y; o.y = (o.y > 0.f) ? o.y : 0.01f * o.y;
    o.z = a6 * inv + bv.z; o.z = (o.z > 0.f) ? o.z : 0.01f * o.z;
    o.w = a7 * inv + bv.w; o.w = (o.w > 0.f) ? o.w : 0.01f * o.w;
    *(float4*)(feat + (size_t)wid * 64 + j * 8 + 4) = o;
  }
}

// ---------------- pooling ----------------

__global__ __launch_bounds__(256) void k_pool(const int* __restrict__ gstart,
                                              const float* __restrict__ feat,
                                              float* __restrict__ out) {
  __shared__ float psum[256];
  int g = blockIdx.x, t = threadIdx.x, f = t & 63, r = t >> 6;
  int s = gstart[g], e = gstart[g + 1];
  float acc = 0.f;
  for (int n = s + r; n < e; n += 4) acc += feat[(size_t)n * 64 + f];
  psum[t] = acc;
  __syncthreads();
  if (r == 0) {
    float tot = psum[f] + psum[64 + f] + psum[128 + f] + psum[192 + f];
    out[g * 64 + f] = tot / fmaxf((float)(e - s), 1.0f);
  }
}

// ---------------- launch ----------------

extern "C" void kernel_launch(void* const* d_in, const int* in_sizes, int n_in,
                              void* d_out, int out_size, void* d_ws, size_t ws_size,
                              hipStream_t stream) {
  const float* x = (const float*)d_in[0];
  const int* ei = (const int*)d_in[1];
  const int* batch = (const int*)d_in[2];
  const float* W1 = (const float*)d_in[3];
  const float* as1 = (const float*)d_in[4];
  const float* ad1 = (const float*)d_in[5];
  const float* b1 = (const float*)d_in[6];
  const float* W2 = (const float*)d_in[7];
  const float* as2 = (const float*)d_in[8];
  const float* ad2 = (const float*)d_in[9];
  const float* b2 = (const float*)d_in[10];
  const float* W3 = (const float*)d_in[11];
  const float* as3 = (const float*)d_in[12];
  const float* ad3 = (const float*)d_in[13];
  const float* b3 = (const float*)d_in[14];
  const float* W4 = (const float*)d_in[15];
  const float* as4 = (const float*)d_in[16];
  const float* ad4 = (const float*)d_in[17];
  const float* b4 = (const float*)d_in[18];
  float* out = (float*)d_out;

  const int N = in_sizes[2];
  const int E = in_sizes[1] / 2;

  size_t off = 0;
  auto carve = [&](size_t bytes) {
    void* q = (char*)d_ws + off;
    off = (off + bytes + 255) & ~(size_t)255;
    return q;
  };
  int* cursor = (int*)carve((size_t)N * 4);
  int* gstart = (int*)carve((size_t)(NGRAPH + 1) * 4);
  unsigned short* ell = (unsigned short*)carve((size_t)N * MAXDEG * 2);
  unsigned short* hbuf = (unsigned short*)carve((size_t)N * 64 * 2);
  float* als = (float*)carve((size_t)N * 4 * 4);
  float* ald = (float*)carve((size_t)N * 4 * 4);
  float* feat = (float*)carve((size_t)N * 64 * 4);
  (void)ws_size;

  int wb = (N + 3) / 4;  // k_A: one wave per node, 4 waves/block

  hipMemsetAsync(cursor, 0, (size_t)N * 4, stream);
  k_build<<<NB, 256, 0, stream>>>(ei, batch, cursor, gstart, ell, E, N);

  k_T<128, 4><<<TB, 256, 0, stream>>>(x, W1, as1, ad1, hbuf, als, ald, N);
  k_A<4><<<wb, 256, 0, stream>>>(cursor, ell, als, ald, hbuf, b1, feat, N);
  k_T<64, 4><<<TB, 256, 0, stream>>>(feat, W2, as2, ad2, hbuf, als, ald, N);
  k_A<4><<<wb, 256, 0, stream>>>(cursor, ell, als, ald, hbuf, b2, feat, N);
  k_T<64, 4><<<TB, 256, 0, stream>>>(feat, W3, as3, ad3, hbuf, als, ald, N);
  k_A<4><<<wb, 256, 0, stream>>>(cursor, ell, als, ald, hbuf, b3, feat, N);
  k_T<64, 1><<<TB, 256, 0, stream>>>(feat, W4, as4, ad4, hbuf, als, ald, N);
  k_A<1><<<wb, 256, 0, stream>>>(cursor, ell, als, ald, hbuf, b4, feat, N);

  k_pool<<<NGRAPH, 256, 0, stream>>>(gstart, feat, out);
}